// Round 1
// baseline (586.559 us; speedup 1.0000x reference)
//
#include <hip/hip_runtime.h>
#include <hip/hip_bf16.h>

// ---------------- types & helpers ----------------
typedef unsigned short u16;
typedef u16  u16x4 __attribute__((ext_vector_type(4)));
typedef u16  u16x8 __attribute__((ext_vector_type(8)));
typedef __bf16 bf16x8 __attribute__((ext_vector_type(8)));
typedef float f32x4 __attribute__((ext_vector_type(4)));

__device__ __forceinline__ float bf2f(u16 v) {
    union { unsigned u; float f; } x; x.u = ((unsigned)v) << 16; return x.f;
}
__device__ __forceinline__ u16 f2bf(float f) {
    union { float f; unsigned u; } x; x.f = f;
    unsigned r = x.u + 0x7fffu + ((x.u >> 16) & 1u);   // RNE
    return (u16)(r >> 16);
}
__device__ __forceinline__ bf16x8 as_bf(u16x8 v) { return __builtin_bit_cast(bf16x8, v); }

// ---------------- tiny elementwise kernels ----------------
__global__ __launch_bounds__(256) void cvt_bf16_k(const float* __restrict__ in,
                                                  u16* __restrict__ out, int n) {
    int i = blockIdx.x * 256 + threadIdx.x;
    if (i < n) out[i] = f2bf(in[i]);
}

__global__ __launch_bounds__(256) void negexp_k(const float* __restrict__ in,
                                                float* __restrict__ out, int n) {
    int i = blockIdx.x * 256 + threadIdx.x;
    if (i < n) out[i] = -__expf(in[i]);
}

// ---------------- RMSNorm: one block (256 thr) per row of 1024 ----------------
__global__ __launch_bounds__(256) void rmsnorm_k(const float* __restrict__ x,
                                                 const float* __restrict__ w,
                                                 u16* __restrict__ h) {
    const int row = blockIdx.x;            // 0..8191
    const float4 v = ((const float4*)(x + (long)row * 1024))[threadIdx.x];
    float ss = v.x * v.x + v.y * v.y + v.z * v.z + v.w * v.w;
    #pragma unroll
    for (int o = 32; o > 0; o >>= 1) ss += __shfl_down(ss, o);
    __shared__ float red[4];
    if ((threadIdx.x & 63) == 0) red[threadIdx.x >> 6] = ss;
    __syncthreads();
    const float tot = red[0] + red[1] + red[2] + red[3];
    const float scale = rsqrtf(tot * (1.0f / 1024.0f) + 1e-5f);
    const float4 wv = ((const float4*)w)[threadIdx.x];
    u16x4 o;
    o[0] = f2bf(v.x * scale * wv.x);
    o[1] = f2bf(v.y * scale * wv.y);
    o[2] = f2bf(v.z * scale * wv.z);
    o[3] = f2bf(v.w * scale * wv.w);
    ((u16x4*)h)[(long)row * 256 + threadIdx.x] = o;
}

// ---------------- bf16 MFMA GEMM: C[M,N] = A[M,K] * B[N,K]^T ----------------
// Block = 256 thr = 4 waves (2x2), tile 128x128, BK=32, 16x16x32 MFMA.
// Reg-staged LDS (round-1 correctness-first; global_load_lds next round).
#define EPI_BF16     0  // Cb[M*N] bf16
#define EPI_XDBL     1  // Cf[M*96] f32; also Cb[M*64] bf16 for cols<64 (dt low-rank)
#define EPI_SOFTPLUS 2  // Cb[M*N] bf16 = softplus(acc + bias[col])
#define EPI_F32      3  // Cf[M*N] f32

template<int EPI>
__global__ __launch_bounds__(256)
void gemm_bt(const u16* __restrict__ A, const u16* __restrict__ Bm,
             u16* __restrict__ Cb, float* __restrict__ Cf,
             const float* __restrict__ bias, int M, int N, int K) {
    __shared__ u16 As[128 * 32];
    __shared__ u16 Bs[128 * 32];
    const int t = threadIdx.x;
    const int lane = t & 63, wave = t >> 6;
    const int wr = wave >> 1, wc = wave & 1;
    const long m0 = (long)blockIdx.x * 128;
    const long n0 = (long)blockIdx.y * 128;

    f32x4 acc[4][4];
    #pragma unroll
    for (int i = 0; i < 4; i++)
        #pragma unroll
        for (int j = 0; j < 4; j++) acc[i][j] = (f32x4)0.0f;

    // staging map: thread t covers rows {t>>2, t>>2+64}, k-cols (t&3)*8..+7
    const int sr = t >> 2;
    const int sc = (t & 3) * 8;
    const long arow0 = m0 + sr, arow1 = m0 + sr + 64;
    long brow0 = n0 + sr, brow1 = n0 + sr + 64;
    if (brow0 > N - 1) brow0 = N - 1;     // clamp for N=96 tile
    if (brow1 > N - 1) brow1 = N - 1;

    const int fr = lane & 15;             // frag row (A) / col (B)
    const int fk = (lane >> 4) * 8;       // frag k offset (8 contiguous bf16)

    for (int k0 = 0; k0 < K; k0 += 32) {
        const u16x8 a0 = *(const u16x8*)&A[arow0 * K + k0 + sc];
        const u16x8 a1 = *(const u16x8*)&A[arow1 * K + k0 + sc];
        const u16x8 b0 = *(const u16x8*)&Bm[brow0 * K + k0 + sc];
        const u16x8 b1 = *(const u16x8*)&Bm[brow1 * K + k0 + sc];
        __syncthreads();
        *(u16x8*)&As[sr * 32 + sc] = a0;
        *(u16x8*)&As[(sr + 64) * 32 + sc] = a1;
        *(u16x8*)&Bs[sr * 32 + sc] = b0;
        *(u16x8*)&Bs[(sr + 64) * 32 + sc] = b1;
        __syncthreads();
        bf16x8 af[4], bfr[4];
        #pragma unroll
        for (int i = 0; i < 4; i++)
            af[i] = as_bf(*(const u16x8*)&As[(wr * 64 + i * 16 + fr) * 32 + fk]);
        #pragma unroll
        for (int j = 0; j < 4; j++)
            bfr[j] = as_bf(*(const u16x8*)&Bs[(wc * 64 + j * 16 + fr) * 32 + fk]);
        #pragma unroll
        for (int i = 0; i < 4; i++)
            #pragma unroll
            for (int j = 0; j < 4; j++)
                acc[i][j] = __builtin_amdgcn_mfma_f32_16x16x32_bf16(af[i], bfr[j], acc[i][j], 0, 0, 0);
    }

    // epilogue: C/D mapping col=lane&15, row=(lane>>4)*4+r  [m89-verified]
    const int rbase = (lane >> 4) * 4;
    #pragma unroll
    for (int i = 0; i < 4; i++) {
        const long grow0 = m0 + wr * 64 + i * 16 + rbase;
        #pragma unroll
        for (int j = 0; j < 4; j++) {
            const long gcol = n0 + wc * 64 + j * 16 + (lane & 15);
            if (gcol >= N) continue;
            #pragma unroll
            for (int r = 0; r < 4; r++) {
                const float v = acc[i][j][r];
                const long row = grow0 + r;
                if constexpr (EPI == EPI_BF16) {
                    Cb[row * (long)N + gcol] = f2bf(v);
                } else if constexpr (EPI == EPI_F32) {
                    Cf[row * (long)N + gcol] = v;
                } else if constexpr (EPI == EPI_SOFTPLUS) {
                    const float xx = v + bias[gcol];
                    const float sp = (xx > 20.0f) ? xx : log1pf(expf(xx));
                    Cb[row * (long)N + gcol] = f2bf(sp);
                } else { // EPI_XDBL
                    Cf[row * (long)N + gcol] = v;
                    if (gcol < 64) Cb[row * 64 + gcol] = f2bf(v);
                }
            }
        }
    }
}

// ---------------- causal depthwise conv (D_CONV=4) + SiLU ----------------
// xi = xz[:, 0:2048] (row stride 4096). One thread per (m, d).
__global__ __launch_bounds__(256)
void conv_silu_k(const u16* __restrict__ xz, const float* __restrict__ cw,
                 const float* __restrict__ cb, u16* __restrict__ xc) {
    const int d = blockIdx.y * 256 + threadIdx.x;   // 0..2047
    const long m = blockIdx.x;                      // 0..8191
    const long lbase = (m >> 12) << 12;             // batch start
    float a = cb[d];
    #pragma unroll
    for (int j = 0; j < 4; j++) {
        const long mj = m - 3 + j;
        if (mj >= lbase) a += bf2f(xz[mj * 4096 + d]) * cw[d * 4 + j];
    }
    const float s = a / (1.0f + __expf(-a));        // SiLU
    xc[m * 2048 + d] = f2bf(s);
}

// ---------------- chunked selective scan ----------------
// h_t = exp(dt*A)*h_{t-1} + (dt*x)*B_t ; 64 chunks x 64 steps.
#define TCH 64
#define NCH 64

// phase 1: per (b,d,chunk) compute P=prod(dA) and q=h_end(from 0). [b][d][c][n]
__global__ __launch_bounds__(256)
void scan_phase1(const u16* __restrict__ dt, const u16* __restrict__ xc,
                 const float* __restrict__ xdbl, const float* __restrict__ Aptr,
                 float* __restrict__ P, float* __restrict__ Q) {
    const int d = blockIdx.y * 256 + threadIdx.x;
    const int c = blockIdx.x, b = blockIdx.z;
    float Ar[16], h[16], p[16];
    #pragma unroll
    for (int n = 0; n < 16; n++) { Ar[n] = Aptr[d * 16 + n]; h[n] = 0.0f; p[n] = 1.0f; }
    const long mbase = (long)b * 4096 + (long)c * TCH;
    for (int ts = 0; ts < TCH; ts++) {
        const long m = mbase + ts;
        const float dtv = bf2f(dt[m * 2048 + d]);
        const float du = dtv * bf2f(xc[m * 2048 + d]);
        const float* Brow = xdbl + m * 96 + 64;
        #pragma unroll
        for (int n = 0; n < 16; n++) {
            const float dA = __expf(dtv * Ar[n]);
            h[n] = h[n] * dA + du * Brow[n];
            p[n] *= dA;
        }
    }
    const long o = (((long)b * 2048 + d) * NCH + c) * 16;
    #pragma unroll
    for (int n = 0; n < 16; n++) { P[o + n] = p[n]; Q[o + n] = h[n]; }
}

// phase 2: sequential over chunks per (b,d,n); overwrites P with h_start.
__global__ __launch_bounds__(256)
void scan_phase2(float* __restrict__ P, const float* __restrict__ Q) {
    const long i = (long)blockIdx.x * 256 + threadIdx.x;   // 65536 = (b*2048+d)*16+n
    const long base = (i >> 4) * (NCH * 16) + (i & 15);
    float hc = 0.0f;
    for (int c = 0; c < NCH; c++) {
        const long o = base + (long)c * 16;
        const float pc = P[o], qc = Q[o];
        P[o] = hc;                  // h_start for this chunk
        hc = pc * hc + qc;
    }
}

// phase 3: recompute with carry, y = (sum_n h*C + xc*D) * silu(z), write bf16.
__global__ __launch_bounds__(256)
void scan_phase3(const u16* __restrict__ dt, const u16* __restrict__ xc,
                 const float* __restrict__ xdbl, const float* __restrict__ Aptr,
                 const float* __restrict__ Hst, const u16* __restrict__ xz,
                 const float* __restrict__ Dp, u16* __restrict__ y) {
    const int d = blockIdx.y * 256 + threadIdx.x;
    const int c = blockIdx.x, b = blockIdx.z;
    float Ar[16], h[16];
    const long hb = (((long)b * 2048 + d) * NCH + c) * 16;
    #pragma unroll
    for (int n = 0; n < 16; n++) { Ar[n] = Aptr[d * 16 + n]; h[n] = Hst[hb + n]; }
    const float Dv = Dp[d];
    const long mbase = (long)b * 4096 + (long)c * TCH;
    for (int ts = 0; ts < TCH; ts++) {
        const long m = mbase + ts;
        const float dtv = bf2f(dt[m * 2048 + d]);
        const float xv  = bf2f(xc[m * 2048 + d]);
        const float zv  = bf2f(xz[m * 4096 + 2048 + d]);
        const float du = dtv * xv;
        const float* Brow = xdbl + m * 96 + 64;
        const float* Crow = xdbl + m * 96 + 80;
        float yv = 0.0f;
        #pragma unroll
        for (int n = 0; n < 16; n++) {
            const float dA = __expf(dtv * Ar[n]);
            h[n] = h[n] * dA + du * Brow[n];
            yv += h[n] * Crow[n];
        }
        yv += xv * Dv;
        const float g = zv / (1.0f + __expf(-zv));
        y[m * 2048 + d] = f2bf(yv * g);
    }
}

// ---------------- launcher ----------------
extern "C" void kernel_launch(void* const* d_in, const int* in_sizes, int n_in,
                              void* d_out, int out_size, void* d_ws, size_t ws_size,
                              hipStream_t stream) {
    const float* x         = (const float*)d_in[0];
    const float* norm_w    = (const float*)d_in[1];
    const float* in_proj_w = (const float*)d_in[2];
    const float* conv_w    = (const float*)d_in[3];
    const float* conv_b    = (const float*)d_in[4];
    const float* x_proj_w  = (const float*)d_in[5];
    const float* dt_proj_w = (const float*)d_in[6];
    const float* dt_proj_b = (const float*)d_in[7];
    const float* A_log     = (const float*)d_in[8];
    const float* Dp        = (const float*)d_in[9];
    const float* out_proj_w= (const float*)d_in[10];

    char* ws = (char*)d_ws;
    size_t off = 0;
    auto alloc = [&](size_t b) { size_t o = off; off += (b + 255) & ~(size_t)255; return o; };
    float* Abuf = (float*)(ws + alloc(2048 * 16 * 4));          // -exp(A_log)
    u16* w_in   = (u16*)(ws + alloc((size_t)4194304 * 2));      // in_proj bf16
    u16* w_xp   = (u16*)(ws + alloc((size_t)196608 * 2));
    u16* w_dt   = (u16*)(ws + alloc((size_t)131072 * 2));
    u16* w_out  = (u16*)(ws + alloc((size_t)2097152 * 2));
    u16* hbuf   = (u16*)(ws + alloc((size_t)8388608 * 2));      // rmsnorm out, M x 1024
    u16* xz     = (u16*)(ws + alloc((size_t)33554432 * 2));     // M x 4096
    u16* xc     = (u16*)(ws + alloc((size_t)16777216 * 2));     // M x 2048
    float* xdbl = (float*)(ws + alloc((size_t)786432 * 4));     // M x 96
    u16* dtr    = (u16*)(ws + alloc((size_t)524288 * 2));       // M x 64 (dt low-rank bf16)
    u16* dtb    = (u16*)(ws + alloc((size_t)16777216 * 2));     // M x 2048 dt (post-softplus)
    u16* ybuf   = (u16*)(ws + alloc((size_t)16777216 * 2));     // M x 2048
    float* P    = (float*)(ws + alloc((size_t)4194304 * 4));    // chunk prod / then h_start
    float* Q    = (float*)(ws + alloc((size_t)4194304 * 4));    // chunk h_end

    cvt_bf16_k<<<16384, 256, 0, stream>>>(in_proj_w, w_in, 4194304);
    cvt_bf16_k<<<768,   256, 0, stream>>>(x_proj_w,  w_xp, 196608);
    cvt_bf16_k<<<512,   256, 0, stream>>>(dt_proj_w, w_dt, 131072);
    cvt_bf16_k<<<8192,  256, 0, stream>>>(out_proj_w, w_out, 2097152);
    negexp_k<<<128, 256, 0, stream>>>(A_log, Abuf, 32768);

    rmsnorm_k<<<8192, 256, 0, stream>>>(x, norm_w, hbuf);

    dim3 g1(64, 32);
    gemm_bt<EPI_BF16><<<g1, 256, 0, stream>>>(hbuf, w_in, xz, nullptr, nullptr, 8192, 4096, 1024);

    dim3 gc(8192, 8);
    conv_silu_k<<<gc, 256, 0, stream>>>(xz, conv_w, conv_b, xc);

    dim3 g2(64, 1);
    gemm_bt<EPI_XDBL><<<g2, 256, 0, stream>>>(xc, w_xp, dtr, xdbl, nullptr, 8192, 96, 2048);

    dim3 g3(64, 16);
    gemm_bt<EPI_SOFTPLUS><<<g3, 256, 0, stream>>>(dtr, w_dt, dtb, nullptr, dt_proj_b, 8192, 2048, 64);

    dim3 gs(NCH, 8, 2);
    scan_phase1<<<gs, 256, 0, stream>>>(dtb, xc, xdbl, Abuf, P, Q);
    scan_phase2<<<256, 256, 0, stream>>>(P, Q);
    scan_phase3<<<gs, 256, 0, stream>>>(dtb, xc, xdbl, Abuf, P, xz, Dp, ybuf);

    dim3 g4(64, 8);
    gemm_bt<EPI_F32><<<g4, 256, 0, stream>>>(ybuf, w_out, nullptr, (float*)d_out, nullptr, 8192, 1024, 2048);
}